// Round 1
// baseline (222.626 us; speedup 1.0000x reference)
//
#include <hip/hip_runtime.h>

// CrossAttention: x[4,2048,512], context[4,2048,512], Wq/Wk/Wv[512,512], Wo[512,512], bo[512]
// out = softmax(QK^T/sqrt(64)) V  -> @Wo + bo.  All-bf16 MFMA pipeline, fp32 accum.

typedef short bf16x8 __attribute__((ext_vector_type(8)));
typedef float f32x4 __attribute__((ext_vector_type(4)));

#define NB 4
#define NN 2048
#define QD 512
#define NHEAD 8
#define DH 64
// log2(e)/sqrt(DH): folded into Q so softmax runs in exp2 domain
#define QSCALE 0.18033688011112042f

__device__ __forceinline__ unsigned short f2bf(float f) {
  unsigned u = __float_as_uint(f);
  unsigned r = (u + 0x7fffu + ((u >> 16) & 1u)) >> 16;
  return (unsigned short)r;
}

// ---------------- convert x / context to bf16 ----------------
__global__ __launch_bounds__(256) void cvt_inputs(const float* __restrict__ x,
                                                  const float* __restrict__ ctx,
                                                  unsigned short* __restrict__ xb,
                                                  unsigned short* __restrict__ cb) {
  int i = blockIdx.x * 256 + threadIdx.x;  // one float4 per thread per array
  const int total = (NB * NN * QD) / 4;    // 1,048,576
  if (i < total) {
    float4 v = ((const float4*)x)[i];
    ushort4 o;
    o.x = f2bf(v.x); o.y = f2bf(v.y); o.z = f2bf(v.z); o.w = f2bf(v.w);
    ((ushort4*)xb)[i] = o;
    float4 w = ((const float4*)ctx)[i];
    ushort4 p;
    p.x = f2bf(w.x); p.y = f2bf(w.y); p.z = f2bf(w.z); p.w = f2bf(w.w);
    ((ushort4*)cb)[i] = p;
  }
}

// ---------------- transpose weights to [col][k] bf16 ----------------
__global__ __launch_bounds__(256) void cvt_weights(const float* __restrict__ Wq, const float* __restrict__ Wk,
                                                   const float* __restrict__ Wv, const float* __restrict__ Wo,
                                                   unsigned short* __restrict__ wqt, unsigned short* __restrict__ wkt,
                                                   unsigned short* __restrict__ wvt, unsigned short* __restrict__ wot) {
  __shared__ float t[32][33];
  const float* W = blockIdx.z == 0 ? Wq : blockIdx.z == 1 ? Wk : blockIdx.z == 2 ? Wv : Wo;
  unsigned short* O = blockIdx.z == 0 ? wqt : blockIdx.z == 1 ? wkt : blockIdx.z == 2 ? wvt : wot;
  int c0 = blockIdx.x * 32, k0 = blockIdx.y * 32;
  int tx = threadIdx.x, ty = threadIdx.y;  // 32 x 8
#pragma unroll
  for (int j = 0; j < 4; j++) t[ty + 8 * j][tx] = W[(k0 + ty + 8 * j) * QD + c0 + tx];
  __syncthreads();
#pragma unroll
  for (int j = 0; j < 4; j++) O[(c0 + ty + 8 * j) * QD + k0 + tx] = f2bf(t[tx][ty + 8 * j]);
}

// ---------------- GEMM: C[r][c] = sum_k A[r][k]*Bt[c][k] ----------------
// 128x128 tile, BK=64, 4 waves (2x2), each wave 64x64 = 4x4 MFMA tiles.
// MODE 0: bf16 out, attention layout [bh][n][64]   (Q with scale, K)
// MODE 1: bf16 out, V transposed [bh][64][m]
// MODE 2: fp32 out + bias (final projection)
template <int MODE>
__global__ __launch_bounds__(256, 2) void gemm_bt(const unsigned short* __restrict__ A,
                                                  const unsigned short* __restrict__ Bt,
                                                  void* __restrict__ Cout,
                                                  const float* __restrict__ bias, float outscale) {
  __shared__ unsigned short sA[128 * 72];  // padded stride 72 (144B = 9*16B, conflict-free-ish)
  __shared__ unsigned short sB[128 * 72];
  const int lane = threadIdx.x & 63, wid = threadIdx.x >> 6;
  const int lo = lane & 15, hi = lane >> 4;
  const int wm = wid >> 1, wn = wid & 1;
  const int r0 = blockIdx.x * 128, c0 = blockIdx.y * 128;
  f32x4 acc[4][4] = {};
  for (int k0 = 0; k0 < QD; k0 += 64) {
    __syncthreads();
#pragma unroll
    for (int i = 0; i < 4; i++) {
      int p = wid * 256 + i * 64 + lane;  // 1024 16B-slots per tile
      int row = p >> 3, ks = p & 7;
      *(bf16x8*)&sA[row * 72 + ks * 8] = *(const bf16x8*)&A[(r0 + row) * QD + k0 + ks * 8];
      *(bf16x8*)&sB[row * 72 + ks * 8] = *(const bf16x8*)&Bt[(c0 + row) * QD + k0 + ks * 8];
    }
    __syncthreads();
#pragma unroll
    for (int kk = 0; kk < 2; kk++) {
      bf16x8 af[4], bfr[4];
#pragma unroll
      for (int t = 0; t < 4; t++) af[t] = *(const bf16x8*)&sA[(wm * 64 + t * 16 + lo) * 72 + (kk * 4 + hi) * 8];
#pragma unroll
      for (int u = 0; u < 4; u++) bfr[u] = *(const bf16x8*)&sB[(wn * 64 + u * 16 + lo) * 72 + (kk * 4 + hi) * 8];
#pragma unroll
      for (int t = 0; t < 4; t++)
#pragma unroll
        for (int u = 0; u < 4; u++)
          acc[t][u] = __builtin_amdgcn_mfma_f32_16x16x32_bf16(af[t], bfr[u], acc[t][u], 0, 0, 0);
    }
  }
  // epilogue: C row=(hi*4+ri), col=lo within each 16x16 tile
#pragma unroll
  for (int t = 0; t < 4; t++)
#pragma unroll
    for (int u = 0; u < 4; u++)
#pragma unroll
      for (int ri = 0; ri < 4; ri++) {
        int r = r0 + wm * 64 + t * 16 + hi * 4 + ri;
        int c = c0 + wn * 64 + u * 16 + lo;
        float v = acc[t][u][ri] * outscale;
        if (MODE == 2) {
          ((float*)Cout)[r * QD + c] = v + bias[c];
        } else if (MODE == 0) {
          int b = r >> 11, n = r & 2047, h = c >> 6, d = c & 63;
          ((unsigned short*)Cout)[(((b << 3) | h) * NN + n) * DH + d] = f2bf(v);
        } else {
          int b = r >> 11, m = r & 2047, h = c >> 6, d = c & 63;
          ((unsigned short*)Cout)[(((b << 3) | h) * DH + d) * NN + m] = f2bf(v);
        }
      }
}

// ---------------- flash attention ----------------
// grid (32 bh, 32 qblk), 256 thr. Each wave: 16 Q rows; block: 64 Q rows.
// KV blocks of 64. Q pre-scaled by log2(e)/8 -> exp2 softmax.
__global__ __launch_bounds__(256, 4) void flash_attn(const unsigned short* __restrict__ Q,
                                                     const unsigned short* __restrict__ K,
                                                     const unsigned short* __restrict__ Vt,
                                                     unsigned short* __restrict__ O) {
  __shared__ unsigned short sK[64 * 72];
  __shared__ unsigned short sV[64 * 72];        // V transposed: row=d, col=j
  __shared__ unsigned short sP[4][16 * 72];     // per-wave P tile [16 rows][64 cols], pad 72
  const int lane = threadIdx.x & 63, wid = threadIdx.x >> 6;
  const int lo = lane & 15, hi = lane >> 4;
  const int bh = blockIdx.x;
  const int q0 = blockIdx.y * 64;

  // Q fragments (A-layout): row=lo, k = s*32 + hi*8 + j  over d
  bf16x8 qf[2];
  const int qrow = q0 + wid * 16 + lo;
  qf[0] = *(const bf16x8*)&Q[(bh * NN + qrow) * DH + hi * 8];
  qf[1] = *(const bf16x8*)&Q[(bh * NN + qrow) * DH + 32 + hi * 8];

  float m_r[4], l_r[4];
  f32x4 oa[4] = {};
#pragma unroll
  for (int r = 0; r < 4; r++) { m_r[r] = -3.0e38f; l_r[r] = 0.f; }

  for (int it = 0; it < NN / 64; it++) {
    int j0 = it * 64;
    __syncthreads();
#pragma unroll
    for (int i = 0; i < 2; i++) {
      int p = wid * 128 + i * 64 + lane;  // 512 slots per tile
      int row = p >> 3, ks = p & 7;
      *(bf16x8*)&sK[row * 72 + ks * 8] = *(const bf16x8*)&K[(bh * NN + j0 + row) * DH + ks * 8];
      *(bf16x8*)&sV[row * 72 + ks * 8] = *(const bf16x8*)&Vt[(bh * DH + row) * NN + j0 + ks * 8];
    }
    __syncthreads();

    // S tiles: 16 rows x 64 cols per wave
    f32x4 s[4];
#pragma unroll
    for (int t = 0; t < 4; t++) {
      f32x4 z = {};
#pragma unroll
      for (int ss = 0; ss < 2; ss++) {
        bf16x8 kf = *(const bf16x8*)&sK[(t * 16 + lo) * 72 + (ss * 4 + hi) * 8];
        z = __builtin_amdgcn_mfma_f32_16x16x32_bf16(qf[ss], kf, z, 0, 0, 0);
      }
      s[t] = z;
    }

    // online softmax (exp2 domain). Row r lives across the 16 lanes sharing `hi`.
    float pm[4];
#pragma unroll
    for (int r = 0; r < 4; r++) pm[r] = fmaxf(fmaxf(s[0][r], s[1][r]), fmaxf(s[2][r], s[3][r]));
#pragma unroll
    for (int off = 1; off < 16; off <<= 1)
#pragma unroll
      for (int r = 0; r < 4; r++) pm[r] = fmaxf(pm[r], __shfl_xor(pm[r], off));
    float al[4], rs[4];
#pragma unroll
    for (int r = 0; r < 4; r++) {
      float mn = fmaxf(m_r[r], pm[r]);
      al[r] = exp2f(m_r[r] - mn);
      m_r[r] = mn;
      rs[r] = 0.f;
    }
#pragma unroll
    for (int t = 0; t < 4; t++)
#pragma unroll
      for (int r = 0; r < 4; r++) {
        float p = exp2f(s[t][r] - m_r[r]);
        s[t][r] = p;
        rs[r] += p;
      }
#pragma unroll
    for (int off = 1; off < 16; off <<= 1)
#pragma unroll
      for (int r = 0; r < 4; r++) rs[r] += __shfl_xor(rs[r], off);
#pragma unroll
    for (int r = 0; r < 4; r++) l_r[r] = l_r[r] * al[r] + rs[r];
#pragma unroll
    for (int dt = 0; dt < 4; dt++)
#pragma unroll
      for (int r = 0; r < 4; r++) oa[dt][r] *= al[r];

    // P -> per-wave LDS (C-layout write), read back in A-layout. Intra-wave only.
    unsigned short* pw = &sP[wid][0];
#pragma unroll
    for (int t = 0; t < 4; t++)
#pragma unroll
      for (int r = 0; r < 4; r++) pw[(hi * 4 + r) * 72 + t * 16 + lo] = f2bf(s[t][r]);

    // PV: O += P[16x64] * V[64x64]
#pragma unroll
    for (int ss = 0; ss < 2; ss++) {
      bf16x8 pa = *(const bf16x8*)&pw[lo * 72 + ss * 32 + hi * 8];
#pragma unroll
      for (int dt = 0; dt < 4; dt++) {
        bf16x8 vb = *(const bf16x8*)&sV[(dt * 16 + lo) * 72 + (ss * 4 + hi) * 8];
        oa[dt] = __builtin_amdgcn_mfma_f32_16x16x32_bf16(pa, vb, oa[dt], 0, 0, 0);
      }
    }
  }

  // normalize + store to o_ws [b][n][h*64+d] bf16
  int b = bh >> 3, h = bh & 7;
#pragma unroll
  for (int r = 0; r < 4; r++) {
    float inv = 1.f / l_r[r];
    int n = q0 + wid * 16 + hi * 4 + r;
#pragma unroll
    for (int dt = 0; dt < 4; dt++)
      O[(b * NN + n) * QD + h * DH + dt * 16 + lo] = f2bf(oa[dt][r] * inv);
  }
}

extern "C" void kernel_launch(void* const* d_in, const int* in_sizes, int n_in,
                              void* d_out, int out_size, void* d_ws, size_t ws_size,
                              hipStream_t stream) {
  const float* x   = (const float*)d_in[0];
  const float* ctx = (const float*)d_in[1];
  const float* Wq  = (const float*)d_in[2];
  const float* Wk  = (const float*)d_in[3];
  const float* Wv  = (const float*)d_in[4];
  const float* Wo  = (const float*)d_in[5];
  const float* bo  = (const float*)d_in[6];
  char* ws = (char*)d_ws;

  unsigned short* xb   = (unsigned short*)(ws);              // 8 MB
  unsigned short* cb   = (unsigned short*)(ws + 8388608);    // 8 MB
  unsigned short* wqt  = (unsigned short*)(ws + 16777216);   // 512 KB each
  unsigned short* wkt  = (unsigned short*)(ws + 17301504);
  unsigned short* wvt  = (unsigned short*)(ws + 17825792);
  unsigned short* wot  = (unsigned short*)(ws + 18350080);
  unsigned short* q_ws = (unsigned short*)(ws + 18874368);   // 8 MB, [bh][n][64]
  unsigned short* k_ws = (unsigned short*)(ws + 27262976);   // 8 MB
  unsigned short* v_ws = (unsigned short*)(ws + 35651584);   // 8 MB, [bh][64][m]
  unsigned short* o_ws = xb;  // alias: xb is dead after the Q projection
  float* out = (float*)d_out;

  cvt_inputs<<<4096, 256, 0, stream>>>(x, ctx, xb, cb);
  cvt_weights<<<dim3(16, 16, 4), dim3(32, 8), 0, stream>>>(Wq, Wk, Wv, Wo, wqt, wkt, wvt, wot);

  gemm_bt<0><<<dim3(64, 4), 256, 0, stream>>>(xb, wqt, (void*)q_ws, nullptr, QSCALE);
  gemm_bt<0><<<dim3(64, 4), 256, 0, stream>>>(cb, wkt, (void*)k_ws, nullptr, 1.0f);
  gemm_bt<1><<<dim3(64, 4), 256, 0, stream>>>(cb, wvt, (void*)v_ws, nullptr, 1.0f);

  flash_attn<<<dim3(32, 32), 256, 0, stream>>>(q_ws, k_ws, v_ws, o_ws);

  gemm_bt<2><<<dim3(64, 4), 256, 0, stream>>>(o_ws, wot, (void*)out, bo, 1.0f);
}

// Round 2
// 133.131 us; speedup vs baseline: 1.6722x; 1.6722x over previous
//
#include <hip/hip_runtime.h>

// CrossAttention: x[4,2048,512], context[4,2048,512], Wq/Wk/Wv[512,512], Wo[512,512], bo[512]
// out = softmax(QK^T/sqrt(64)) V -> @Wo + bo.  All-bf16 MFMA pipeline, fp32 accum.
// R2: swapped-QK^T flash attn (32x32x16, lane-local softmax, cvt_pk+permlane32_swap),
//     global_load_lds staging everywhere (m97 GEMM structure).

typedef short bf16x8 __attribute__((ext_vector_type(8)));
typedef float f32x4 __attribute__((ext_vector_type(4)));
typedef float f32x16 __attribute__((ext_vector_type(16)));

#define NB 4
#define NN 2048
#define QD 512
#define DH 64
// log2(e)/sqrt(DH): folded into Q so softmax runs in exp2 domain
#define QSCALE 0.18033688011112042f

__device__ __forceinline__ unsigned short f2bf(float f) {
  unsigned u = __float_as_uint(f);
  unsigned r = (u + 0x7fffu + ((u >> 16) & 1u)) >> 16;
  return (unsigned short)r;
}

__device__ __forceinline__ unsigned cvtpk(float a, float b) {
  unsigned r;
  asm("v_cvt_pk_bf16_f32 %0, %1, %2" : "=v"(r) : "v"(a), "v"(b));
  return r;
}

__device__ __forceinline__ void pl32swap(unsigned& a, unsigned& b) {
  asm("v_permlane32_swap_b32 %0, %1" : "+v"(a), "+v"(b));
}

__device__ __forceinline__ void gload16(const void* g, void* l) {
  __builtin_amdgcn_global_load_lds((const __attribute__((address_space(1))) unsigned int*)g,
                                   (__attribute__((address_space(3))) unsigned int*)l, 16, 0, 0);
}

// ---------------- convert x / context to bf16 ----------------
__global__ __launch_bounds__(256) void cvt_inputs(const float* __restrict__ x,
                                                  const float* __restrict__ ctx,
                                                  unsigned short* __restrict__ xb,
                                                  unsigned short* __restrict__ cb) {
  int i = blockIdx.x * 256 + threadIdx.x;
  const int total = (NB * NN * QD) / 4;
  if (i < total) {
    float4 v = ((const float4*)x)[i];
    ushort4 o;
    o.x = f2bf(v.x); o.y = f2bf(v.y); o.z = f2bf(v.z); o.w = f2bf(v.w);
    ((ushort4*)xb)[i] = o;
    float4 w = ((const float4*)ctx)[i];
    ushort4 p;
    p.x = f2bf(w.x); p.y = f2bf(w.y); p.z = f2bf(w.z); p.w = f2bf(w.w);
    ((ushort4*)cb)[i] = p;
  }
}

// ---------------- transpose weights to [col][k] bf16 ----------------
__global__ __launch_bounds__(256) void cvt_weights(const float* __restrict__ Wq, const float* __restrict__ Wk,
                                                   const float* __restrict__ Wv, const float* __restrict__ Wo,
                                                   unsigned short* __restrict__ wqt, unsigned short* __restrict__ wkt,
                                                   unsigned short* __restrict__ wvt, unsigned short* __restrict__ wot) {
  __shared__ float t[32][33];
  const float* W = blockIdx.z == 0 ? Wq : blockIdx.z == 1 ? Wk : blockIdx.z == 2 ? Wv : Wo;
  unsigned short* O = blockIdx.z == 0 ? wqt : blockIdx.z == 1 ? wkt : blockIdx.z == 2 ? wvt : wot;
  int c0 = blockIdx.x * 32, k0 = blockIdx.y * 32;
  int tx = threadIdx.x, ty = threadIdx.y;  // 32 x 8
#pragma unroll
  for (int j = 0; j < 4; j++) t[ty + 8 * j][tx] = W[(k0 + ty + 8 * j) * QD + c0 + tx];
  __syncthreads();
#pragma unroll
  for (int j = 0; j < 4; j++) O[(c0 + ty + 8 * j) * QD + k0 + tx] = f2bf(t[tx][ty + 8 * j]);
}

// ---------------- GEMM: C[r][c] = sum_k A[r][k]*Bt[c][k]  (m97 structure) ----------------
// 128x128 tile, BK=64, 4 waves (2x2), global_load_lds staging, linear LDS [128][64].
template <int MODE>
__global__ __launch_bounds__(256, 2) void gemm_bt(const unsigned short* __restrict__ A,
                                                  const unsigned short* __restrict__ Bt,
                                                  void* __restrict__ Cout,
                                                  const float* __restrict__ bias, float outscale) {
  __shared__ __align__(16) unsigned short sA[128 * 64];
  __shared__ __align__(16) unsigned short sB[128 * 64];
  const int lane = threadIdx.x & 63, wid = threadIdx.x >> 6;
  const int lo = lane & 15, hi = lane >> 4;
  const int wm = wid >> 1, wn = wid & 1;
  const int r0 = blockIdx.x * 128, c0 = blockIdx.y * 128;
  const int r8 = lane >> 3, c8l = lane & 7;
  f32x4 acc[4][4] = {};
  for (int k0 = 0; k0 < QD; k0 += 64) {
    __syncthreads();
#pragma unroll
    for (int i = 0; i < 4; i++) {
      int chunk = wid * 4 + i;       // 16 chunks of 8 rows
      int row = chunk * 8 + r8;
      gload16(&A[(r0 + row) * QD + k0 + c8l * 8], (char*)sA + chunk * 1024);
      gload16(&Bt[(c0 + row) * QD + k0 + c8l * 8], (char*)sB + chunk * 1024);
    }
    __syncthreads();
#pragma unroll
    for (int kk = 0; kk < 2; kk++) {
      bf16x8 af[4], bfr[4];
#pragma unroll
      for (int t = 0; t < 4; t++) af[t] = *(const bf16x8*)&sA[(wm * 64 + t * 16 + lo) * 64 + (kk * 4 + hi) * 8];
#pragma unroll
      for (int u = 0; u < 4; u++) bfr[u] = *(const bf16x8*)&sB[(wn * 64 + u * 16 + lo) * 64 + (kk * 4 + hi) * 8];
#pragma unroll
      for (int t = 0; t < 4; t++)
#pragma unroll
        for (int u = 0; u < 4; u++)
          acc[t][u] = __builtin_amdgcn_mfma_f32_16x16x32_bf16(af[t], bfr[u], acc[t][u], 0, 0, 0);
    }
  }
#pragma unroll
  for (int t = 0; t < 4; t++)
#pragma unroll
    for (int u = 0; u < 4; u++)
#pragma unroll
      for (int ri = 0; ri < 4; ri++) {
        int r = r0 + wm * 64 + t * 16 + hi * 4 + ri;
        int c = c0 + wn * 64 + u * 16 + lo;
        float v = acc[t][u][ri] * outscale;
        if (MODE == 2) {
          ((float*)Cout)[r * QD + c] = v + bias[c];
        } else if (MODE == 0) {
          int b = r >> 11, n = r & 2047, h = c >> 6, d = c & 63;
          ((unsigned short*)Cout)[(((b << 3) | h) * NN + n) * DH + d] = f2bf(v);
        } else {
          int b = r >> 11, m = r & 2047, h = c >> 6, d = c & 63;
          ((unsigned short*)Cout)[(((b << 3) | h) * DH + d) * NN + m] = f2bf(v);
        }
      }
}

// ---------------- flash attention, swapped QK^T ----------------
// grid (32 bh, 16 qblk), 256 thr = 4 waves. Each wave owns 32 q rows; each lane owns
// ONE query (q = lane&31); lanes L and L^32 split that query's 64 key-scores (32 each).
// KV blocks of 64 staged in LDS (double-buffered, XOR source-swizzle, global_load_lds).
__global__ __launch_bounds__(256, 2) void flash_attn(const unsigned short* __restrict__ Q,
                                                     const unsigned short* __restrict__ K,
                                                     const unsigned short* __restrict__ Vt,
                                                     unsigned short* __restrict__ O) {
  __shared__ __align__(16) char sKV[2][16384];  // [buf][K 64x64 | V^T 64x64]
  const int lane = threadIdx.x & 63, wid = threadIdx.x >> 6;
  const int l31 = lane & 31, hi = lane >> 5;
  const int r8 = lane >> 3, c8l = lane & 7;
  const int bh = blockIdx.x;
  const int bhK = bh * NN;   // K row base
  const int bhV = bh * DH;   // Vt row base
  const int qrow = blockIdx.y * 128 + wid * 32 + l31;

  // Q fragments (B-operand): col=q(=l31), k(d) = ks*16 + hi*8 + j
  bf16x8 qf[4];
#pragma unroll
  for (int ks = 0; ks < 4; ks++)
    qf[ks] = *(const bf16x8*)&Q[(bhK + qrow) * DH + ks * 16 + hi * 8];

  // precomputed swizzled LDS byte addresses (buf 0)
  int kaddr[2][4];
#pragma unroll
  for (int g = 0; g < 2; g++)
#pragma unroll
    for (int ks = 0; ks < 4; ks++) {
      int row = g * 32 + l31;
      kaddr[g][ks] = row * 128 + (((ks * 2 + hi) ^ (row & 7)) << 4);
    }
  int vaddr[2][2][2];
#pragma unroll
  for (int dt = 0; dt < 2; dt++)
#pragma unroll
    for (int g = 0; g < 2; g++)
#pragma unroll
      for (int s = 0; s < 2; s++) {
        int d = dt * 32 + l31;
        vaddr[dt][g][s] = 8192 + d * 128 + (((g * 4 + s * 2 + hi) ^ (d & 7)) << 4);
      }

#define STAGE(J0, BUF)                                                                              \
  do {                                                                                              \
    char* kb_ = (char*)sKV + (BUF) * 16384;                                                         \
    _Pragma("unroll") for (int i_ = 0; i_ < 2; ++i_) {                                              \
      int rw = wid * 16 + i_ * 8 + r8;                                                              \
      gload16(&K[(bhK + (J0) + rw) * DH + ((c8l ^ (rw & 7)) * 8)], kb_ + (wid * 2 + i_) * 1024);    \
      gload16(&Vt[(bhV + rw) * NN + (J0) + ((c8l ^ (rw & 7)) * 8)],                                 \
              kb_ + 8192 + (wid * 2 + i_) * 1024);                                                  \
    }                                                                                               \
  } while (0)

  float m = -3.0e38f, l = 0.f;
  f32x16 o[2] = {};

  STAGE(0, 0);
  __syncthreads();

  for (int it = 0; it < NN / 64; ++it) {
    const char* buf = (const char*)sKV + (it & 1) * 16384;
    if (it + 1 < NN / 64) STAGE((it + 1) * 64, (it + 1) & 1);

    // S^T[key][q] = K . Q^T  (2 key-tiles of 32, K-dim = d in 4 slices of 16)
    f32x16 st[2];
    st[0] = (f32x16){};
    st[1] = (f32x16){};
#pragma unroll
    for (int g = 0; g < 2; g++)
#pragma unroll
      for (int ks = 0; ks < 4; ks++) {
        bf16x8 kf = *(const bf16x8*)(buf + kaddr[g][ks]);
        st[g] = __builtin_amdgcn_mfma_f32_32x32x16_bf16(kf, qf[ks], st[g], 0, 0, 0);
      }

    // lane-local softmax over the 32 values this lane holds, pair-combined with lane^32
    float pm = -3.0e38f;
#pragma unroll
    for (int g = 0; g < 2; g++)
#pragma unroll
      for (int c = 0; c < 16; c++) pm = fmaxf(pm, st[g][c]);
    pm = fmaxf(pm, __shfl_xor(pm, 32));
    if (__any(pm - m > 8.f)) {  // defer-max (T13), exp2 domain: p bounded by 2^8
      float mn = fmaxf(m, pm);
      float al = exp2f(m - mn);
      m = mn;
      l *= al;
#pragma unroll
      for (int dt = 0; dt < 2; dt++)
#pragma unroll
        for (int c = 0; c < 16; c++) o[dt][c] *= al;
    }
    float rs = 0.f;
#pragma unroll
    for (int g = 0; g < 2; g++)
#pragma unroll
      for (int c = 0; c < 16; c++) {
        float p = exp2f(st[g][c] - m);
        st[g][c] = p;
        rs += p;
      }
    rs += __shfl_xor(rs, 32);
    l += rs;

    // P -> bf16 B-fragments: per key-tile g, slice s: keys (hi*8..+8) of slice.
    // (w0,w2)=swap(pk(c0,c1),pk(c4,c5)); (w1,w3)=swap(pk(c2,c3),pk(c6,c7)); cb=s*8.
    bf16x8 pf[2][2];
#pragma unroll
    for (int g = 0; g < 2; g++)
#pragma unroll
      for (int s = 0; s < 2; s++) {
        const int cb = s * 8;
        unsigned a0 = cvtpk(st[g][cb + 0], st[g][cb + 1]);
        unsigned a1 = cvtpk(st[g][cb + 2], st[g][cb + 3]);
        unsigned b0 = cvtpk(st[g][cb + 4], st[g][cb + 5]);
        unsigned b1 = cvtpk(st[g][cb + 6], st[g][cb + 7]);
        pl32swap(a0, b0);
        pl32swap(a1, b1);
        union { unsigned u[4]; bf16x8 v; } pu;
        pu.u[0] = a0; pu.u[1] = a1; pu.u[2] = b0; pu.u[3] = b1;
        pf[g][s] = pu.v;
      }

    // O^T[d][q] += V^T . P^T
#pragma unroll
    for (int dt = 0; dt < 2; dt++)
#pragma unroll
      for (int g = 0; g < 2; g++)
#pragma unroll
        for (int s = 0; s < 2; s++) {
          bf16x8 vf = *(const bf16x8*)(buf + vaddr[dt][g][s]);
          o[dt] = __builtin_amdgcn_mfma_f32_32x32x16_bf16(vf, pf[g][s], o[dt], 0, 0, 0);
        }

    __syncthreads();  // drains staging (next buf ready) + joins readers before overwrite
  }

  // normalize + store: O^T reg c of tile dt -> d = dt*32 + (c&3) + 8*(c>>2) + 4*hi
  float inv = 1.f / l;
  int b = bh >> 3, h = bh & 7;
#pragma unroll
  for (int dt = 0; dt < 2; dt++)
#pragma unroll
    for (int cg = 0; cg < 4; cg++) {
      ushort4 w;
      w.x = f2bf(o[dt][cg * 4 + 0] * inv);
      w.y = f2bf(o[dt][cg * 4 + 1] * inv);
      w.z = f2bf(o[dt][cg * 4 + 2] * inv);
      w.w = f2bf(o[dt][cg * 4 + 3] * inv);
      int d0 = dt * 32 + cg * 8 + hi * 4;
      *(ushort4*)&O[(b * NN + qrow) * QD + h * DH + d0] = w;
    }
#undef STAGE
}

extern "C" void kernel_launch(void* const* d_in, const int* in_sizes, int n_in,
                              void* d_out, int out_size, void* d_ws, size_t ws_size,
                              hipStream_t stream) {
  const float* x   = (const float*)d_in[0];
  const float* ctx = (const float*)d_in[1];
  const float* Wq  = (const float*)d_in[2];
  const float* Wk  = (const float*)d_in[3];
  const float* Wv  = (const float*)d_in[4];
  const float* Wo  = (const float*)d_in[5];
  const float* bo  = (const float*)d_in[6];
  char* ws = (char*)d_ws;

  unsigned short* xb   = (unsigned short*)(ws);              // 8 MB
  unsigned short* cb   = (unsigned short*)(ws + 8388608);    // 8 MB
  unsigned short* wqt  = (unsigned short*)(ws + 16777216);   // 512 KB each
  unsigned short* wkt  = (unsigned short*)(ws + 17301504);
  unsigned short* wvt  = (unsigned short*)(ws + 17825792);
  unsigned short* wot  = (unsigned short*)(ws + 18350080);
  unsigned short* q_ws = (unsigned short*)(ws + 18874368);   // 8 MB, [bh][n][64]
  unsigned short* k_ws = (unsigned short*)(ws + 27262976);   // 8 MB, [bh][m][64]
  unsigned short* v_ws = (unsigned short*)(ws + 35651584);   // 8 MB, [bh][64][m]
  unsigned short* o_ws = xb;  // alias: xb dead after Q projection
  float* out = (float*)d_out;

  cvt_inputs<<<4096, 256, 0, stream>>>(x, ctx, xb, cb);
  cvt_weights<<<dim3(16, 16, 4), dim3(32, 8), 0, stream>>>(Wq, Wk, Wv, Wo, wqt, wkt, wvt, wot);

  gemm_bt<0><<<dim3(64, 4), 256, 0, stream>>>(xb, wqt, (void*)q_ws, nullptr, QSCALE);
  gemm_bt<0><<<dim3(64, 4), 256, 0, stream>>>(cb, wkt, (void*)k_ws, nullptr, 1.0f);
  gemm_bt<1><<<dim3(64, 4), 256, 0, stream>>>(cb, wvt, (void*)v_ws, nullptr, 1.0f);

  flash_attn<<<dim3(32, 16), 256, 0, stream>>>(q_ws, k_ws, v_ws, o_ws);

  gemm_bt<2><<<dim3(64, 4), 256, 0, stream>>>(o_ws, wot, (void*)out, bo, 1.0f);
}